// Round 1
// baseline (958.977 us; speedup 1.0000x reference)
//
#include <hip/hip_runtime.h>
#include <math.h>

#define BB 4096
#define DD 256
#define GG 100
#define GAMMA_C 0.8f
#define RHO_C 8.0f
#define ALPHA_C 0.5f
#define EPS_C 1e-14f

// ---------------- block reduction helpers (256 threads = 4 waves) -----------
__device__ inline float blockReduceSum(float v, float* lds) {
    for (int o = 32; o > 0; o >>= 1) v += __shfl_down(v, o);
    int lane = threadIdx.x & 63, wid = threadIdx.x >> 6;
    if (lane == 0) lds[wid] = v;
    __syncthreads();
    if (threadIdx.x == 0) {
        float r = lds[0];
        int nw = blockDim.x >> 6;
        for (int w = 1; w < nw; w++) r += lds[w];
        lds[0] = r;
    }
    __syncthreads();
    float r = lds[0];
    __syncthreads();
    return r;
}

__device__ inline float blockReduceMax(float v, float* lds) {
    for (int o = 32; o > 0; o >>= 1) v = fmaxf(v, __shfl_down(v, o));
    int lane = threadIdx.x & 63, wid = threadIdx.x >> 6;
    if (lane == 0) lds[wid] = v;
    __syncthreads();
    if (threadIdx.x == 0) {
        float r = lds[0];
        int nw = blockDim.x >> 6;
        for (int w = 1; w < nw; w++) r = fmaxf(r, lds[w]);
        lds[0] = r;
    }
    __syncthreads();
    float r = lds[0];
    __syncthreads();
    return r;
}

// ---------------- 1) L2 row-normalize both batches --------------------------
// grid 2*BB blocks, 256 threads (= DD)
__global__ void norm_kernel(const float* __restrict__ zis,
                            const float* __restrict__ zjs,
                            float* __restrict__ zn, float* __restrict__ wn) {
    __shared__ float lds[8];
    int r = blockIdx.x;
    const float* src;
    float* dst;
    int row;
    if (r < BB) { src = zis; dst = zn; row = r; }
    else        { src = zjs; dst = wn; row = r - BB; }
    float v = src[row * DD + threadIdx.x];
    float ss = blockReduceSum(v * v, lds);
    float nrm = sqrtf(ss);
    float inv = 1.0f / fmaxf(nrm, 1e-12f);
    dst[row * DD + threadIdx.x] = v * inv;
}

// ---------------- 2) sim = Zn * Wn^T  (fp32, 64x64 tile) --------------------
#define LP 65  // LDS pitch: 2-way max bank aliasing (free on CDNA4)
__global__ void __launch_bounds__(256) gemm_kernel(const float* __restrict__ A,
                                                   const float* __restrict__ Bm,
                                                   float* __restrict__ C) {
    __shared__ float As[64 * LP];
    __shared__ float Bs[64 * LP];
    int tx = threadIdx.x & 15;   // n-quad
    int ty = threadIdx.x >> 4;   // m-quad
    int bm = blockIdx.y * 64, bn = blockIdx.x * 64;
    float acc[4][4] = {};
    for (int k0 = 0; k0 < DD; k0 += 64) {
        for (int q = 0; q < 4; q++) {
            int l = threadIdx.x + q * 256;  // float4 slot 0..1023
            int row = l >> 4;               // 0..63
            int c4 = l & 15;                // 0..15
            float4 av = *(const float4*)&A[(size_t)(bm + row) * DD + k0 + c4 * 4];
            float4 bv = *(const float4*)&Bm[(size_t)(bn + row) * DD + k0 + c4 * 4];
            As[(c4 * 4 + 0) * LP + row] = av.x;
            As[(c4 * 4 + 1) * LP + row] = av.y;
            As[(c4 * 4 + 2) * LP + row] = av.z;
            As[(c4 * 4 + 3) * LP + row] = av.w;
            Bs[(c4 * 4 + 0) * LP + row] = bv.x;
            Bs[(c4 * 4 + 1) * LP + row] = bv.y;
            Bs[(c4 * 4 + 2) * LP + row] = bv.z;
            Bs[(c4 * 4 + 3) * LP + row] = bv.w;
        }
        __syncthreads();
        for (int k = 0; k < 64; k++) {
            float a0 = As[k * LP + ty * 4 + 0];
            float a1 = As[k * LP + ty * 4 + 1];
            float a2 = As[k * LP + ty * 4 + 2];
            float a3 = As[k * LP + ty * 4 + 3];
            float b0 = Bs[k * LP + tx * 4 + 0];
            float b1 = Bs[k * LP + tx * 4 + 1];
            float b2 = Bs[k * LP + tx * 4 + 2];
            float b3 = Bs[k * LP + tx * 4 + 3];
            acc[0][0] += a0 * b0; acc[0][1] += a0 * b1; acc[0][2] += a0 * b2; acc[0][3] += a0 * b3;
            acc[1][0] += a1 * b0; acc[1][1] += a1 * b1; acc[1][2] += a1 * b2; acc[1][3] += a1 * b3;
            acc[2][0] += a2 * b0; acc[2][1] += a2 * b1; acc[2][2] += a2 * b2; acc[2][3] += a2 * b3;
            acc[3][0] += a3 * b0; acc[3][1] += a3 * b1; acc[3][2] += a3 * b2; acc[3][3] += a3 * b3;
        }
        __syncthreads();
    }
    for (int m = 0; m < 4; m++) {
        float4 v = make_float4(acc[m][0], acc[m][1], acc[m][2], acc[m][3]);
        *(float4*)&C[(size_t)(bm + ty * 4 + m) * BB + bn + tx * 4] = v;
    }
}

// acc layout (floats): [0]=lossI_sum [1]=lossT_sum [2..101]=gradI [102..201]=cntI
//                      [202..301]=gradT [302..401]=cntT
// ---------------- 3) row pass (image side) ----------------------------------
__global__ void __launch_bounds__(256) row_kernel(const float* __restrict__ sim,
        const float* __restrict__ sI, const float* __restrict__ bI,
        const float* __restrict__ tausI, const int* __restrict__ ids,
        const int* __restrict__ ginfoI, const float* __restrict__ pI,
        float* __restrict__ acc) {
    __shared__ float lds[8];
    int i = blockIdx.x;
    int id = ids[i];
    float tau = tausI[id];
    float invTau = 1.0f / tau;
    float oldb = bI[id];
    float olds = sI[id];
    const float* rowp = sim + (size_t)i * BB;
    float diag = rowp[i];
    float vals[16];
    float vmax = -INFINITY;
    for (int q = 0; q < 16; q++) {
        float v = rowp[threadIdx.x + q * 256];
        vals[q] = v;
        vmax = fmaxf(vmax, v);
    }
    float rmax = blockReduceMax(vmax, lds);
    float bnew = fmaxf((rmax - diag) * invTau, oldb);  // diag term (0) included via rmax>=diag
    float g = 0.f, wsum = 0.f;
    for (int q = 0; q < 16; q++) {
        int j = threadIdx.x + q * 256;
        if (j != i) {
            float dv = vals[q] - diag;
            float e = expf(dv * invTau - bnew);
            g += e;
            wsum += e * dv;
        }
    }
    g = blockReduceSum(g, lds);
    wsum = blockReduceSum(wsum, lds);
    if (threadIdx.x == 0) {
        float snew = (1.f - GAMMA_C) * olds * expf(oldb - bnew) + GAMMA_C * g;
        float sc = fmaxf(snew, EPS_C);
        int gid = ginfoI[id];
        float gw = (float)GG * pI[gid];
        float loss = gw * wsum / sc;
        float F = tau * (logf(sc) + bnew + RHO_C);
        atomicAdd(&acc[0], loss);
        atomicAdd(&acc[2 + gid], F);
        atomicAdd(&acc[102 + gid], 1.0f);
    }
}

// ---------------- 4) column pass (text side) --------------------------------
// grid 64 blocks; each block owns 64 columns; 256 threads = 64 cols x 4 row-groups
__global__ void __launch_bounds__(256) col_kernel(const float* __restrict__ sim,
        const float* __restrict__ sT, const float* __restrict__ bT,
        const float* __restrict__ tausT, const int* __restrict__ ids,
        const int* __restrict__ ginfoT, const float* __restrict__ pT,
        float* __restrict__ acc) {
    __shared__ float red[4][64];
    __shared__ float colDiag[64], colInvTau[64], colBnew[64];
    int c = threadIdx.x & 63;
    int rg = threadIdx.x >> 6;
    int j = blockIdx.x * 64 + c;
    if (rg == 0) {
        int id = ids[j];
        colDiag[c] = sim[(size_t)j * BB + j];
        colInvTau[c] = 1.0f / tausT[id];
    }
    __syncthreads();
    float diag = colDiag[c], invTau = colInvTau[c];
    // pass 1: column max of raw sim
    float vmax = -INFINITY;
    for (int r = rg; r < BB; r += 4) vmax = fmaxf(vmax, sim[(size_t)r * BB + j]);
    red[rg][c] = vmax;
    __syncthreads();
    if (rg == 0) {
        float m = fmaxf(fmaxf(red[0][c], red[1][c]), fmaxf(red[2][c], red[3][c]));
        int id = ids[j];
        colBnew[c] = fmaxf((m - diag) * invTau, bT[id]);
    }
    __syncthreads();
    float bnew = colBnew[c];
    // pass 2: exp sums
    float g = 0.f, wsum = 0.f;
    for (int r = rg; r < BB; r += 4) {
        float v = sim[(size_t)r * BB + j];
        if (r != j) {
            float dv = v - diag;
            float e = expf(dv * invTau - bnew);
            g += e;
            wsum += e * dv;
        }
    }
    red[rg][c] = g;
    __syncthreads();
    float gsum = 0.f;
    if (rg == 0) gsum = red[0][c] + red[1][c] + red[2][c] + red[3][c];
    __syncthreads();
    red[rg][c] = wsum;
    __syncthreads();
    if (rg == 0) {
        float wsumT = red[0][c] + red[1][c] + red[2][c] + red[3][c];
        int id = ids[j];
        float tau = tausT[id];
        float oldb = bT[id];
        float olds = sT[id];
        float snew = (1.f - GAMMA_C) * olds * expf(oldb - bnew) + GAMMA_C * gsum;
        float sc = fmaxf(snew, EPS_C);
        int gid = ginfoT[id];
        float gw = (float)GG * pT[gid];
        float loss = gw * wsumT / sc;
        float F = tau * (logf(sc) + bnew + RHO_C);
        atomicAdd(&acc[1], loss);
        atomicAdd(&acc[202 + gid], F);
        atomicAdd(&acc[302 + gid], 1.0f);
    }
}

// ---------------- 5) finalize: p updates + total loss -----------------------
__global__ void final_kernel(const float* __restrict__ acc,
                             const float* __restrict__ zI, const float* __restrict__ zT,
                             const float* __restrict__ pI, const float* __restrict__ pT,
                             float* __restrict__ out) {
    __shared__ float sumsI[2], sumsT[2];
    int g = threadIdx.x;  // 128 threads
    float npI = 0.f, npT = 0.f;
    if (g < GG) {
        float cntI = fmaxf(acc[102 + g], 1.f);
        float gpI = acc[2 + g] / cntI;
        float zi = (1.f - GAMMA_C) * zI[g] + GAMMA_C * gpI;
        float ghpI = -logf(pI[g] + EPS_C) - 1.f;
        float ti = fminf(fmaxf(zi + ghpI, -5.f), 5.f);
        npI = pI[g] * expf(0.02f * ti);

        float cntT = fmaxf(acc[302 + g], 1.f);
        float gpT = acc[202 + g] / cntT;
        float zt = (1.f - GAMMA_C) * zT[g] + GAMMA_C * gpT;
        float ghpT = -logf(pT[g] + EPS_C) - 1.f;
        float tt = fminf(fmaxf(zt + ghpT, -5.f), 5.f);
        npT = pT[g] * expf(0.02f * tt);
    }
    float vI = npI, vT = npT;
    for (int o = 32; o > 0; o >>= 1) {
        vI += __shfl_down(vI, o);
        vT += __shfl_down(vT, o);
    }
    int wid = threadIdx.x >> 6, lane = threadIdx.x & 63;
    if (lane == 0) { sumsI[wid] = vI; sumsT[wid] = vT; }
    __syncthreads();
    float sumI = sumsI[0] + sumsI[1];
    float sumT = sumsT[0] + sumsT[1];
    if (g < GG) {
        out[1 + g] = npI / sumI;
        out[101 + g] = npT / sumT;
    }
    if (threadIdx.x == 0) {
        out[0] = ALPHA_C * (acc[0] / (float)BB) + (1.f - ALPHA_C) * (acc[1] / (float)BB);
    }
}

extern "C" void kernel_launch(void* const* d_in, const int* in_sizes, int n_in,
                              void* d_out, int out_size, void* d_ws, size_t ws_size,
                              hipStream_t stream) {
    const float* zis   = (const float*)d_in[0];
    const float* zjs   = (const float*)d_in[1];
    const float* s_I   = (const float*)d_in[2];
    const float* s_T   = (const float*)d_in[3];
    const float* b_I   = (const float*)d_in[4];
    const float* b_T   = (const float*)d_in[5];
    const float* z_I   = (const float*)d_in[6];
    const float* z_T   = (const float*)d_in[7];
    const float* p_I   = (const float*)d_in[8];
    const float* p_T   = (const float*)d_in[9];
    const float* tausI = (const float*)d_in[10];
    const float* tausT = (const float*)d_in[11];
    const int*   ids   = (const int*)d_in[12];
    const int*   gInfI = (const int*)d_in[13];
    const int*   gInfT = (const int*)d_in[14];
    float* out = (float*)d_out;

    float* ws = (float*)d_ws;
    float* zn  = ws;                                   // BB*DD
    float* wn  = zn + (size_t)BB * DD;                 // BB*DD
    float* sim = wn + (size_t)BB * DD;                 // BB*BB
    float* acc = sim + (size_t)BB * BB;                // 402

    hipMemsetAsync(acc, 0, 402 * sizeof(float), stream);
    norm_kernel<<<2 * BB, 256, 0, stream>>>(zis, zjs, zn, wn);
    gemm_kernel<<<dim3(64, 64), 256, 0, stream>>>(zn, wn, sim);
    row_kernel<<<BB, 256, 0, stream>>>(sim, s_I, b_I, tausI, ids, gInfI, p_I, acc);
    col_kernel<<<64, 256, 0, stream>>>(sim, s_T, b_T, tausT, ids, gInfT, p_T, acc);
    final_kernel<<<1, 128, 0, stream>>>(acc, z_I, z_T, p_I, p_T, out);
}

// Round 2
// 502.696 us; speedup vs baseline: 1.9077x; 1.9077x over previous
//
#include <hip/hip_runtime.h>
#include <math.h>

#define BB 4096
#define DD 256
#define GG 100
#define GAMMA_C 0.8f
#define RHO_C 8.0f
#define ALPHA_C 0.5f
#define EPS_C 1e-14f
#define RSTRIPES 16   // row stripes for column pass (BB/256)

// ---------------- block reduction helpers (256 threads = 4 waves) -----------
__device__ inline float blockReduceSum(float v, float* lds) {
    for (int o = 32; o > 0; o >>= 1) v += __shfl_down(v, o);
    int lane = threadIdx.x & 63, wid = threadIdx.x >> 6;
    if (lane == 0) lds[wid] = v;
    __syncthreads();
    if (threadIdx.x == 0) {
        float r = lds[0];
        int nw = blockDim.x >> 6;
        for (int w = 1; w < nw; w++) r += lds[w];
        lds[0] = r;
    }
    __syncthreads();
    float r = lds[0];
    __syncthreads();
    return r;
}

__device__ inline float blockReduceMax(float v, float* lds) {
    for (int o = 32; o > 0; o >>= 1) v = fmaxf(v, __shfl_down(v, o));
    int lane = threadIdx.x & 63, wid = threadIdx.x >> 6;
    if (lane == 0) lds[wid] = v;
    __syncthreads();
    if (threadIdx.x == 0) {
        float r = lds[0];
        int nw = blockDim.x >> 6;
        for (int w = 1; w < nw; w++) r = fmaxf(r, lds[w]);
        lds[0] = r;
    }
    __syncthreads();
    float r = lds[0];
    __syncthreads();
    return r;
}

// ---------------- 1) L2 row-normalize both batches --------------------------
__global__ void norm_kernel(const float* __restrict__ zis,
                            const float* __restrict__ zjs,
                            float* __restrict__ zn, float* __restrict__ wn) {
    __shared__ float lds[8];
    int r = blockIdx.x;
    const float* src;
    float* dst;
    int row;
    if (r < BB) { src = zis; dst = zn; row = r; }
    else        { src = zjs; dst = wn; row = r - BB; }
    float v = src[row * DD + threadIdx.x];
    float ss = blockReduceSum(v * v, lds);
    float nrm = sqrtf(ss);
    float inv = 1.0f / fmaxf(nrm, 1e-12f);
    dst[row * DD + threadIdx.x] = v * inv;
}

// ---------------- 2) sim = Zn * Wn^T  (fp32, 64x64 tile) --------------------
#define LP 65
__global__ void __launch_bounds__(256) gemm_kernel(const float* __restrict__ A,
                                                   const float* __restrict__ Bm,
                                                   float* __restrict__ C) {
    __shared__ float As[64 * LP];
    __shared__ float Bs[64 * LP];
    int tx = threadIdx.x & 15;
    int ty = threadIdx.x >> 4;
    int bm = blockIdx.y * 64, bn = blockIdx.x * 64;
    float acc[4][4] = {};
    for (int k0 = 0; k0 < DD; k0 += 64) {
        for (int q = 0; q < 4; q++) {
            int l = threadIdx.x + q * 256;
            int row = l >> 4;
            int c4 = l & 15;
            float4 av = *(const float4*)&A[(size_t)(bm + row) * DD + k0 + c4 * 4];
            float4 bv = *(const float4*)&Bm[(size_t)(bn + row) * DD + k0 + c4 * 4];
            As[(c4 * 4 + 0) * LP + row] = av.x;
            As[(c4 * 4 + 1) * LP + row] = av.y;
            As[(c4 * 4 + 2) * LP + row] = av.z;
            As[(c4 * 4 + 3) * LP + row] = av.w;
            Bs[(c4 * 4 + 0) * LP + row] = bv.x;
            Bs[(c4 * 4 + 1) * LP + row] = bv.y;
            Bs[(c4 * 4 + 2) * LP + row] = bv.z;
            Bs[(c4 * 4 + 3) * LP + row] = bv.w;
        }
        __syncthreads();
        for (int k = 0; k < 64; k++) {
            float a0 = As[k * LP + ty * 4 + 0];
            float a1 = As[k * LP + ty * 4 + 1];
            float a2 = As[k * LP + ty * 4 + 2];
            float a3 = As[k * LP + ty * 4 + 3];
            float b0 = Bs[k * LP + tx * 4 + 0];
            float b1 = Bs[k * LP + tx * 4 + 1];
            float b2 = Bs[k * LP + tx * 4 + 2];
            float b3 = Bs[k * LP + tx * 4 + 3];
            acc[0][0] += a0 * b0; acc[0][1] += a0 * b1; acc[0][2] += a0 * b2; acc[0][3] += a0 * b3;
            acc[1][0] += a1 * b0; acc[1][1] += a1 * b1; acc[1][2] += a1 * b2; acc[1][3] += a1 * b3;
            acc[2][0] += a2 * b0; acc[2][1] += a2 * b1; acc[2][2] += a2 * b2; acc[2][3] += a2 * b3;
            acc[3][0] += a3 * b0; acc[3][1] += a3 * b1; acc[3][2] += a3 * b2; acc[3][3] += a3 * b3;
        }
        __syncthreads();
    }
    for (int m = 0; m < 4; m++) {
        float4 v = make_float4(acc[m][0], acc[m][1], acc[m][2], acc[m][3]);
        *(float4*)&C[(size_t)(bm + ty * 4 + m) * BB + bn + tx * 4] = v;
    }
}

// acc layout: [0]=lossI [1]=lossT [2..101]=gradI [102..201]=cntI
//             [202..301]=gradT [302..401]=cntT
// ---------------- 3) row pass (image side) ----------------------------------
__global__ void __launch_bounds__(256) row_kernel(const float* __restrict__ sim,
        const float* __restrict__ sI, const float* __restrict__ bI,
        const float* __restrict__ tausI, const int* __restrict__ ids,
        const int* __restrict__ ginfoI, const float* __restrict__ pI,
        float* __restrict__ acc) {
    __shared__ float lds[8];
    int i = blockIdx.x;
    int id = ids[i];
    float tau = tausI[id];
    float invTau = 1.0f / tau;
    float oldb = bI[id];
    float olds = sI[id];
    const float* rowp = sim + (size_t)i * BB;
    float diag = rowp[i];
    float vals[16];
    float vmax = -INFINITY;
    for (int q = 0; q < 16; q++) {
        float v = rowp[threadIdx.x + q * 256];
        vals[q] = v;
        vmax = fmaxf(vmax, v);
    }
    float rmax = blockReduceMax(vmax, lds);
    float bnew = fmaxf((rmax - diag) * invTau, oldb);
    float g = 0.f, wsum = 0.f;
    for (int q = 0; q < 16; q++) {
        int j = threadIdx.x + q * 256;
        if (j != i) {
            float dv = vals[q] - diag;
            float e = expf(dv * invTau - bnew);
            g += e;
            wsum += e * dv;
        }
    }
    g = blockReduceSum(g, lds);
    wsum = blockReduceSum(wsum, lds);
    if (threadIdx.x == 0) {
        float snew = (1.f - GAMMA_C) * olds * expf(oldb - bnew) + GAMMA_C * g;
        float sc = fmaxf(snew, EPS_C);
        int gid = ginfoI[id];
        float gw = (float)GG * pI[gid];
        float loss = gw * wsum / sc;
        float F = tau * (logf(sc) + bnew + RHO_C);
        atomicAdd(&acc[0], loss);
        atomicAdd(&acc[2 + gid], F);
        atomicAdd(&acc[102 + gid], 1.0f);
    }
}

// ---------------- 4a) column max partials -----------------------------------
// grid (64, RSTRIPES); block 256 = 64 cols x 4 row-groups; 256 rows per block
__global__ void __launch_bounds__(256) colmax_kernel(const float* __restrict__ sim,
                                                     float* __restrict__ pmax) {
    __shared__ float red[4][64];
    int c = threadIdx.x & 63;
    int rg = threadIdx.x >> 6;
    int j = blockIdx.x * 64 + c;
    int r0 = blockIdx.y * (BB / RSTRIPES);
    float vmax = -INFINITY;
    for (int r = r0 + rg; r < r0 + BB / RSTRIPES; r += 4)
        vmax = fmaxf(vmax, sim[(size_t)r * BB + j]);
    red[rg][c] = vmax;
    __syncthreads();
    if (rg == 0) {
        float m = fmaxf(fmaxf(red[0][c], red[1][c]), fmaxf(red[2][c], red[3][c]));
        pmax[blockIdx.y * BB + j] = m;
    }
}

// ---------------- 4b) reduce partial maxes -> bnew per column ---------------
__global__ void __launch_bounds__(256) colbnew_kernel(const float* __restrict__ pmax,
        const float* __restrict__ sim, const float* __restrict__ bT,
        const float* __restrict__ tausT, const int* __restrict__ ids,
        float* __restrict__ colb) {
    int j = blockIdx.x * 256 + threadIdx.x;
    float m = -INFINITY;
    for (int s = 0; s < RSTRIPES; s++) m = fmaxf(m, pmax[s * BB + j]);
    int id = ids[j];
    float diag = sim[(size_t)j * BB + j];
    float invTau = 1.0f / tausT[id];
    colb[j] = fmaxf((m - diag) * invTau, bT[id]);
}

// ---------------- 4c) column exp-sum partials -------------------------------
__global__ void __launch_bounds__(256) colsum_kernel(const float* __restrict__ sim,
        const float* __restrict__ colb, const float* __restrict__ tausT,
        const int* __restrict__ ids,
        float* __restrict__ pg, float* __restrict__ pw) {
    __shared__ float redg[4][64];
    __shared__ float redw[4][64];
    __shared__ float cDiag[64], cInvTau[64], cB[64];
    int c = threadIdx.x & 63;
    int rg = threadIdx.x >> 6;
    int j = blockIdx.x * 64 + c;
    if (rg == 0) {
        cDiag[c] = sim[(size_t)j * BB + j];
        cInvTau[c] = 1.0f / tausT[ids[j]];
        cB[c] = colb[j];
    }
    __syncthreads();
    float diag = cDiag[c], invTau = cInvTau[c], bnew = cB[c];
    int r0 = blockIdx.y * (BB / RSTRIPES);
    float g = 0.f, wsum = 0.f;
    for (int r = r0 + rg; r < r0 + BB / RSTRIPES; r += 4) {
        float v = sim[(size_t)r * BB + j];
        if (r != j) {
            float dv = v - diag;
            float e = expf(dv * invTau - bnew);
            g += e;
            wsum += e * dv;
        }
    }
    redg[rg][c] = g;
    redw[rg][c] = wsum;
    __syncthreads();
    if (rg == 0) {
        pg[blockIdx.y * BB + j] = redg[0][c] + redg[1][c] + redg[2][c] + redg[3][c];
        pw[blockIdx.y * BB + j] = redw[0][c] + redw[1][c] + redw[2][c] + redw[3][c];
    }
}

// ---------------- 4d) finalize columns --------------------------------------
__global__ void __launch_bounds__(256) colfin_kernel(const float* __restrict__ pg,
        const float* __restrict__ pw, const float* __restrict__ colb,
        const float* __restrict__ sT, const float* __restrict__ bT,
        const float* __restrict__ tausT, const int* __restrict__ ids,
        const int* __restrict__ ginfoT, const float* __restrict__ pT,
        float* __restrict__ acc) {
    int j = blockIdx.x * 256 + threadIdx.x;
    float g = 0.f, wsum = 0.f;
    for (int s = 0; s < RSTRIPES; s++) {
        g += pg[s * BB + j];
        wsum += pw[s * BB + j];
    }
    int id = ids[j];
    float tau = tausT[id];
    float bnew = colb[j];
    float snew = (1.f - GAMMA_C) * sT[id] * expf(bT[id] - bnew) + GAMMA_C * g;
    float sc = fmaxf(snew, EPS_C);
    int gid = ginfoT[id];
    float gw = (float)GG * pT[gid];
    float loss = gw * wsum / sc;
    float F = tau * (logf(sc) + bnew + RHO_C);
    atomicAdd(&acc[1], loss);
    atomicAdd(&acc[202 + gid], F);
    atomicAdd(&acc[302 + gid], 1.0f);
}

// ---------------- 5) finalize: p updates + total loss -----------------------
__global__ void final_kernel(const float* __restrict__ acc,
                             const float* __restrict__ zI, const float* __restrict__ zT,
                             const float* __restrict__ pI, const float* __restrict__ pT,
                             float* __restrict__ out) {
    __shared__ float sumsI[2], sumsT[2];
    int g = threadIdx.x;  // 128 threads
    float npI = 0.f, npT = 0.f;
    if (g < GG) {
        float cntI = fmaxf(acc[102 + g], 1.f);
        float gpI = acc[2 + g] / cntI;
        float zi = (1.f - GAMMA_C) * zI[g] + GAMMA_C * gpI;
        float ghpI = -logf(pI[g] + EPS_C) - 1.f;
        float ti = fminf(fmaxf(zi + ghpI, -5.f), 5.f);
        npI = pI[g] * expf(0.02f * ti);

        float cntT = fmaxf(acc[302 + g], 1.f);
        float gpT = acc[202 + g] / cntT;
        float zt = (1.f - GAMMA_C) * zT[g] + GAMMA_C * gpT;
        float ghpT = -logf(pT[g] + EPS_C) - 1.f;
        float tt = fminf(fmaxf(zt + ghpT, -5.f), 5.f);
        npT = pT[g] * expf(0.02f * tt);
    }
    float vI = npI, vT = npT;
    for (int o = 32; o > 0; o >>= 1) {
        vI += __shfl_down(vI, o);
        vT += __shfl_down(vT, o);
    }
    int wid = threadIdx.x >> 6, lane = threadIdx.x & 63;
    if (lane == 0) { sumsI[wid] = vI; sumsT[wid] = vT; }
    __syncthreads();
    float sumI = sumsI[0] + sumsI[1];
    float sumT = sumsT[0] + sumsT[1];
    if (g < GG) {
        out[1 + g] = npI / sumI;
        out[101 + g] = npT / sumT;
    }
    if (threadIdx.x == 0) {
        out[0] = ALPHA_C * (acc[0] / (float)BB) + (1.f - ALPHA_C) * (acc[1] / (float)BB);
    }
}

extern "C" void kernel_launch(void* const* d_in, const int* in_sizes, int n_in,
                              void* d_out, int out_size, void* d_ws, size_t ws_size,
                              hipStream_t stream) {
    const float* zis   = (const float*)d_in[0];
    const float* zjs   = (const float*)d_in[1];
    const float* s_I   = (const float*)d_in[2];
    const float* s_T   = (const float*)d_in[3];
    const float* b_I   = (const float*)d_in[4];
    const float* b_T   = (const float*)d_in[5];
    const float* z_I   = (const float*)d_in[6];
    const float* z_T   = (const float*)d_in[7];
    const float* p_I   = (const float*)d_in[8];
    const float* p_T   = (const float*)d_in[9];
    const float* tausI = (const float*)d_in[10];
    const float* tausT = (const float*)d_in[11];
    const int*   ids   = (const int*)d_in[12];
    const int*   gInfI = (const int*)d_in[13];
    const int*   gInfT = (const int*)d_in[14];
    float* out = (float*)d_out;

    float* ws = (float*)d_ws;
    float* zn   = ws;                                  // BB*DD
    float* wn   = zn + (size_t)BB * DD;                // BB*DD
    float* sim  = wn + (size_t)BB * DD;                // BB*BB
    float* acc  = sim + (size_t)BB * BB;               // 402
    float* pmax = acc + 512;                           // RSTRIPES*BB
    float* colb = pmax + (size_t)RSTRIPES * BB;        // BB
    float* pg   = colb + BB;                           // RSTRIPES*BB
    float* pw   = pg + (size_t)RSTRIPES * BB;          // RSTRIPES*BB

    hipMemsetAsync(acc, 0, 402 * sizeof(float), stream);
    norm_kernel<<<2 * BB, 256, 0, stream>>>(zis, zjs, zn, wn);
    gemm_kernel<<<dim3(64, 64), 256, 0, stream>>>(zn, wn, sim);
    row_kernel<<<BB, 256, 0, stream>>>(sim, s_I, b_I, tausI, ids, gInfI, p_I, acc);
    colmax_kernel<<<dim3(64, RSTRIPES), 256, 0, stream>>>(sim, pmax);
    colbnew_kernel<<<BB / 256, 256, 0, stream>>>(pmax, sim, b_T, tausT, ids, colb);
    colsum_kernel<<<dim3(64, RSTRIPES), 256, 0, stream>>>(sim, colb, tausT, ids, pg, pw);
    colfin_kernel<<<BB / 256, 256, 0, stream>>>(pg, pw, colb, s_T, b_T, tausT, ids,
                                                gInfT, p_T, acc);
    final_kernel<<<1, 128, 0, stream>>>(acc, z_I, z_T, p_I, p_T, out);
}

// Round 3
// 375.024 us; speedup vs baseline: 2.5571x; 1.3404x over previous
//
#include <hip/hip_runtime.h>
#include <hip/hip_bf16.h>
#include <math.h>

#define BB 4096
#define DD 256
#define GG 100
#define GAMMA_C 0.8f
#define RHO_C 8.0f
#define ALPHA_C 0.5f
#define EPS_C 1e-14f
#define RSTRIPES 16

typedef __bf16 bf16x8 __attribute__((ext_vector_type(8)));
typedef float f32x4 __attribute__((ext_vector_type(4)));

__device__ inline void gl2lds16(const void* g, void* l) {
    // async global->LDS, 16B per lane; LDS dest = wave-uniform base + lane*16
    __builtin_amdgcn_global_load_lds((__attribute__((address_space(1))) void*)(void*)g,
                                     (__attribute__((address_space(3))) void*)l, 16, 0, 0);
}

// ---------------- block reduction helpers -----------------------------------
__device__ inline float blockReduceSum(float v, float* lds) {
    for (int o = 32; o > 0; o >>= 1) v += __shfl_down(v, o);
    int lane = threadIdx.x & 63, wid = threadIdx.x >> 6;
    if (lane == 0) lds[wid] = v;
    __syncthreads();
    if (threadIdx.x == 0) {
        float r = lds[0];
        int nw = blockDim.x >> 6;
        for (int w = 1; w < nw; w++) r += lds[w];
        lds[0] = r;
    }
    __syncthreads();
    float r = lds[0];
    __syncthreads();
    return r;
}

__device__ inline float blockReduceMax(float v, float* lds) {
    for (int o = 32; o > 0; o >>= 1) v = fmaxf(v, __shfl_down(v, o));
    int lane = threadIdx.x & 63, wid = threadIdx.x >> 6;
    if (lane == 0) lds[wid] = v;
    __syncthreads();
    if (threadIdx.x == 0) {
        float r = lds[0];
        int nw = blockDim.x >> 6;
        for (int w = 1; w < nw; w++) r = fmaxf(r, lds[w]);
        lds[0] = r;
    }
    __syncthreads();
    float r = lds[0];
    __syncthreads();
    return r;
}

// ---------------- 1) L2 normalize + split into bf16 hi/lo -------------------
__global__ void norm_kernel(const float* __restrict__ zis,
                            const float* __restrict__ zjs,
                            ushort* __restrict__ zhi, ushort* __restrict__ zlo,
                            ushort* __restrict__ whi, ushort* __restrict__ wlo) {
    __shared__ float lds[8];
    int r = blockIdx.x;
    const float* src;
    ushort *dhi, *dlo;
    int row;
    if (r < BB) { src = zis; dhi = zhi; dlo = zlo; row = r; }
    else        { src = zjs; dhi = whi; dlo = wlo; row = r - BB; }
    float v = src[row * DD + threadIdx.x];
    float ss = blockReduceSum(v * v, lds);
    float inv = 1.0f / fmaxf(sqrtf(ss), 1e-12f);
    float nv = v * inv;
    __hip_bfloat16 h = __float2bfloat16(nv);
    float hf = __bfloat162float(h);
    __hip_bfloat16 l = __float2bfloat16(nv - hf);
    dhi[row * DD + threadIdx.x] = *(ushort*)&h;
    dlo[row * DD + threadIdx.x] = *(ushort*)&l;
}

// ---------------- 2) sim = Z*W^T via split-bf16 MFMA (3 products) -----------
// 128x128 tile, 4 waves each owning 64x64, 16x16x32 bf16 MFMA
__global__ void __launch_bounds__(256) gemm_mfma(const ushort* __restrict__ Ahi,
                                                 const ushort* __restrict__ Alo,
                                                 const ushort* __restrict__ Bhi,
                                                 const ushort* __restrict__ Blo,
                                                 float* __restrict__ C) {
    __shared__ ushort sAhi[128 * 32];
    __shared__ ushort sAlo[128 * 32];
    __shared__ ushort sBhi[128 * 32];
    __shared__ ushort sBlo[128 * 32];

    int lane = threadIdx.x & 63;
    int wv = threadIdx.x >> 6;
    int wm = wv >> 1, wn = wv & 1;   // 2x2 waves -> 64x64 each
    int bm = blockIdx.y * 128, bn = blockIdx.x * 128;
    int ml = lane & 15, kq = lane >> 4;
    int koff = kq * 8;

    f32x4 acc[4][4] = {};

    for (int k0 = 0; k0 < DD; k0 += 32) {
        // ---- stage 4 tiles (128x32 bf16 each) via async global->LDS ----
        for (int i = 0; i < 2; i++) {
            int cbase = i * 256 + wv * 64;       // wave-uniform chunk base
            int c = cbase + lane;                // 16B chunk id, 0..511
            int row = c >> 2;
            int col = (c & 3) * 8;
            size_t ga = (size_t)(bm + row) * DD + k0 + col;
            size_t gb = (size_t)(bn + row) * DD + k0 + col;
            int lofs = cbase * 8;                // ushort offset of wave base
            gl2lds16(&Ahi[ga], &sAhi[lofs]);
            gl2lds16(&Alo[ga], &sAlo[lofs]);
            gl2lds16(&Bhi[gb], &sBhi[lofs]);
            gl2lds16(&Blo[gb], &sBlo[lofs]);
        }
        __syncthreads();   // drains vmcnt -> staging complete

        bf16x8 ah[4], al[4], bh[4], bl[4];
        for (int t = 0; t < 4; t++) {
            int ar = wm * 64 + t * 16 + ml;
            ah[t] = *(const bf16x8*)&sAhi[ar * 32 + koff];
            al[t] = *(const bf16x8*)&sAlo[ar * 32 + koff];
            int br = wn * 64 + t * 16 + ml;
            bh[t] = *(const bf16x8*)&sBhi[br * 32 + koff];
            bl[t] = *(const bf16x8*)&sBlo[br * 32 + koff];
        }
        for (int t = 0; t < 4; t++)
            for (int u = 0; u < 4; u++) {
                acc[t][u] = __builtin_amdgcn_mfma_f32_16x16x32_bf16(ah[t], bh[u], acc[t][u], 0, 0, 0);
                acc[t][u] = __builtin_amdgcn_mfma_f32_16x16x32_bf16(ah[t], bl[u], acc[t][u], 0, 0, 0);
                acc[t][u] = __builtin_amdgcn_mfma_f32_16x16x32_bf16(al[t], bh[u], acc[t][u], 0, 0, 0);
            }
        __syncthreads();   // protect LDS before next stage
    }

    // epilogue: C/D layout col=lane&15, row=(lane>>4)*4+reg  [m89/m91]
    for (int t = 0; t < 4; t++) {
        int rbase = bm + wm * 64 + t * 16 + kq * 4;
        for (int u = 0; u < 4; u++) {
            int cc = bn + wn * 64 + u * 16 + ml;
            f32x4 v = acc[t][u];
            C[(size_t)(rbase + 0) * BB + cc] = v.x;
            C[(size_t)(rbase + 1) * BB + cc] = v.y;
            C[(size_t)(rbase + 2) * BB + cc] = v.z;
            C[(size_t)(rbase + 3) * BB + cc] = v.w;
        }
    }
}

// acc layout: [0]=lossI [1]=lossT [2..101]=gradI [102..201]=cntI
//             [202..301]=gradT [302..401]=cntT
// ---------------- 3) row pass (image side) ----------------------------------
__global__ void __launch_bounds__(256) row_kernel(const float* __restrict__ sim,
        const float* __restrict__ sI, const float* __restrict__ bI,
        const float* __restrict__ tausI, const int* __restrict__ ids,
        const int* __restrict__ ginfoI, const float* __restrict__ pI,
        float* __restrict__ acc) {
    __shared__ float lds[8];
    int i = blockIdx.x;
    int id = ids[i];
    float tau = tausI[id];
    float invTau = 1.0f / tau;
    float oldb = bI[id];
    float olds = sI[id];
    const float* rowp = sim + (size_t)i * BB;
    float diag = rowp[i];
    float vals[16];
    float vmax = -INFINITY;
    for (int q = 0; q < 16; q++) {
        float v = rowp[threadIdx.x + q * 256];
        vals[q] = v;
        vmax = fmaxf(vmax, v);
    }
    float rmax = blockReduceMax(vmax, lds);
    float bnew = fmaxf((rmax - diag) * invTau, oldb);
    float g = 0.f, wsum = 0.f;
    for (int q = 0; q < 16; q++) {
        int j = threadIdx.x + q * 256;
        if (j != i) {
            float dv = vals[q] - diag;
            float e = expf(dv * invTau - bnew);
            g += e;
            wsum += e * dv;
        }
    }
    g = blockReduceSum(g, lds);
    wsum = blockReduceSum(wsum, lds);
    if (threadIdx.x == 0) {
        float snew = (1.f - GAMMA_C) * olds * expf(oldb - bnew) + GAMMA_C * g;
        float sc = fmaxf(snew, EPS_C);
        int gid = ginfoI[id];
        float gw = (float)GG * pI[gid];
        float loss = gw * wsum / sc;
        float F = tau * (logf(sc) + bnew + RHO_C);
        atomicAdd(&acc[0], loss);
        atomicAdd(&acc[2 + gid], F);
        atomicAdd(&acc[102 + gid], 1.0f);
    }
}

// ---------------- 4a) column max partials -----------------------------------
__global__ void __launch_bounds__(256) colmax_kernel(const float* __restrict__ sim,
                                                     float* __restrict__ pmax) {
    __shared__ float red[4][64];
    int c = threadIdx.x & 63;
    int rg = threadIdx.x >> 6;
    int j = blockIdx.x * 64 + c;
    int r0 = blockIdx.y * (BB / RSTRIPES);
    float vmax = -INFINITY;
    for (int r = r0 + rg; r < r0 + BB / RSTRIPES; r += 4)
        vmax = fmaxf(vmax, sim[(size_t)r * BB + j]);
    red[rg][c] = vmax;
    __syncthreads();
    if (rg == 0) {
        float m = fmaxf(fmaxf(red[0][c], red[1][c]), fmaxf(red[2][c], red[3][c]));
        pmax[blockIdx.y * BB + j] = m;
    }
}

// ---------------- 4b) reduce partial maxes -> bnew per column ---------------
__global__ void __launch_bounds__(256) colbnew_kernel(const float* __restrict__ pmax,
        const float* __restrict__ sim, const float* __restrict__ bT,
        const float* __restrict__ tausT, const int* __restrict__ ids,
        float* __restrict__ colb) {
    int j = blockIdx.x * 256 + threadIdx.x;
    float m = -INFINITY;
    for (int s = 0; s < RSTRIPES; s++) m = fmaxf(m, pmax[s * BB + j]);
    int id = ids[j];
    float diag = sim[(size_t)j * BB + j];
    float invTau = 1.0f / tausT[id];
    colb[j] = fmaxf((m - diag) * invTau, bT[id]);
}

// ---------------- 4c) column exp-sum partials -------------------------------
__global__ void __launch_bounds__(256) colsum_kernel(const float* __restrict__ sim,
        const float* __restrict__ colb, const float* __restrict__ tausT,
        const int* __restrict__ ids,
        float* __restrict__ pg, float* __restrict__ pw) {
    __shared__ float redg[4][64];
    __shared__ float redw[4][64];
    __shared__ float cDiag[64], cInvTau[64], cB[64];
    int c = threadIdx.x & 63;
    int rg = threadIdx.x >> 6;
    int j = blockIdx.x * 64 + c;
    if (rg == 0) {
        cDiag[c] = sim[(size_t)j * BB + j];
        cInvTau[c] = 1.0f / tausT[ids[j]];
        cB[c] = colb[j];
    }
    __syncthreads();
    float diag = cDiag[c], invTau = cInvTau[c], bnew = cB[c];
    int r0 = blockIdx.y * (BB / RSTRIPES);
    float g = 0.f, wsum = 0.f;
    for (int r = r0 + rg; r < r0 + BB / RSTRIPES; r += 4) {
        float v = sim[(size_t)r * BB + j];
        if (r != j) {
            float dv = v - diag;
            float e = expf(dv * invTau - bnew);
            g += e;
            wsum += e * dv;
        }
    }
    redg[rg][c] = g;
    redw[rg][c] = wsum;
    __syncthreads();
    if (rg == 0) {
        pg[blockIdx.y * BB + j] = redg[0][c] + redg[1][c] + redg[2][c] + redg[3][c];
        pw[blockIdx.y * BB + j] = redw[0][c] + redw[1][c] + redw[2][c] + redw[3][c];
    }
}

// ---------------- 4d) finalize columns --------------------------------------
__global__ void __launch_bounds__(256) colfin_kernel(const float* __restrict__ pg,
        const float* __restrict__ pw, const float* __restrict__ colb,
        const float* __restrict__ sT, const float* __restrict__ bT,
        const float* __restrict__ tausT, const int* __restrict__ ids,
        const int* __restrict__ ginfoT, const float* __restrict__ pT,
        float* __restrict__ acc) {
    int j = blockIdx.x * 256 + threadIdx.x;
    float g = 0.f, wsum = 0.f;
    for (int s = 0; s < RSTRIPES; s++) {
        g += pg[s * BB + j];
        wsum += pw[s * BB + j];
    }
    int id = ids[j];
    float tau = tausT[id];
    float bnew = colb[j];
    float snew = (1.f - GAMMA_C) * sT[id] * expf(bT[id] - bnew) + GAMMA_C * g;
    float sc = fmaxf(snew, EPS_C);
    int gid = ginfoT[id];
    float gw = (float)GG * pT[gid];
    float loss = gw * wsum / sc;
    float F = tau * (logf(sc) + bnew + RHO_C);
    atomicAdd(&acc[1], loss);
    atomicAdd(&acc[202 + gid], F);
    atomicAdd(&acc[302 + gid], 1.0f);
}

// ---------------- 5) finalize: p updates + total loss -----------------------
__global__ void final_kernel(const float* __restrict__ acc,
                             const float* __restrict__ zI, const float* __restrict__ zT,
                             const float* __restrict__ pI, const float* __restrict__ pT,
                             float* __restrict__ out) {
    __shared__ float sumsI[2], sumsT[2];
    int g = threadIdx.x;  // 128 threads
    float npI = 0.f, npT = 0.f;
    if (g < GG) {
        float cntI = fmaxf(acc[102 + g], 1.f);
        float gpI = acc[2 + g] / cntI;
        float zi = (1.f - GAMMA_C) * zI[g] + GAMMA_C * gpI;
        float ghpI = -logf(pI[g] + EPS_C) - 1.f;
        float ti = fminf(fmaxf(zi + ghpI, -5.f), 5.f);
        npI = pI[g] * expf(0.02f * ti);

        float cntT = fmaxf(acc[302 + g], 1.f);
        float gpT = acc[202 + g] / cntT;
        float zt = (1.f - GAMMA_C) * zT[g] + GAMMA_C * gpT;
        float ghpT = -logf(pT[g] + EPS_C) - 1.f;
        float tt = fminf(fmaxf(zt + ghpT, -5.f), 5.f);
        npT = pT[g] * expf(0.02f * tt);
    }
    float vI = npI, vT = npT;
    for (int o = 32; o > 0; o >>= 1) {
        vI += __shfl_down(vI, o);
        vT += __shfl_down(vT, o);
    }
    int wid = threadIdx.x >> 6, lane = threadIdx.x & 63;
    if (lane == 0) { sumsI[wid] = vI; sumsT[wid] = vT; }
    __syncthreads();
    float sumI = sumsI[0] + sumsI[1];
    float sumT = sumsT[0] + sumsT[1];
    if (g < GG) {
        out[1 + g] = npI / sumI;
        out[101 + g] = npT / sumT;
    }
    if (threadIdx.x == 0) {
        out[0] = ALPHA_C * (acc[0] / (float)BB) + (1.f - ALPHA_C) * (acc[1] / (float)BB);
    }
}

extern "C" void kernel_launch(void* const* d_in, const int* in_sizes, int n_in,
                              void* d_out, int out_size, void* d_ws, size_t ws_size,
                              hipStream_t stream) {
    const float* zis   = (const float*)d_in[0];
    const float* zjs   = (const float*)d_in[1];
    const float* s_I   = (const float*)d_in[2];
    const float* s_T   = (const float*)d_in[3];
    const float* b_I   = (const float*)d_in[4];
    const float* b_T   = (const float*)d_in[5];
    const float* z_I   = (const float*)d_in[6];
    const float* z_T   = (const float*)d_in[7];
    const float* p_I   = (const float*)d_in[8];
    const float* p_T   = (const float*)d_in[9];
    const float* tausI = (const float*)d_in[10];
    const float* tausT = (const float*)d_in[11];
    const int*   ids   = (const int*)d_in[12];
    const int*   gInfI = (const int*)d_in[13];
    const int*   gInfT = (const int*)d_in[14];
    float* out = (float*)d_out;

    char* ws = (char*)d_ws;
    float* sim  = (float*)ws;                          // BB*BB f32 = 64 MB
    ushort* zhi = (ushort*)(sim + (size_t)BB * BB);    // BB*DD u16
    ushort* zlo = zhi + (size_t)BB * DD;
    ushort* whi = zlo + (size_t)BB * DD;
    ushort* wlo = whi + (size_t)BB * DD;
    float* acc  = (float*)(wlo + (size_t)BB * DD);     // 402 (pad to 512)
    float* pmax = acc + 512;                           // RSTRIPES*BB
    float* colb = pmax + (size_t)RSTRIPES * BB;        // BB
    float* pg   = colb + BB;                           // RSTRIPES*BB
    float* pw   = pg + (size_t)RSTRIPES * BB;          // RSTRIPES*BB

    hipMemsetAsync(acc, 0, 402 * sizeof(float), stream);
    norm_kernel<<<2 * BB, 256, 0, stream>>>(zis, zjs, zhi, zlo, whi, wlo);
    gemm_mfma<<<dim3(32, 32), 256, 0, stream>>>(zhi, zlo, whi, wlo, sim);
    row_kernel<<<BB, 256, 0, stream>>>(sim, s_I, b_I, tausI, ids, gInfI, p_I, acc);
    colmax_kernel<<<dim3(64, RSTRIPES), 256, 0, stream>>>(sim, pmax);
    colbnew_kernel<<<BB / 256, 256, 0, stream>>>(pmax, sim, b_T, tausT, ids, colb);
    colsum_kernel<<<dim3(64, RSTRIPES), 256, 0, stream>>>(sim, colb, tausT, ids, pg, pw);
    colfin_kernel<<<BB / 256, 256, 0, stream>>>(pg, pw, colb, s_T, b_T, tausT, ids,
                                                gInfT, p_T, acc);
    final_kernel<<<1, 128, 0, stream>>>(acc, z_I, z_T, p_I, p_T, out);
}

// Round 4
// 346.795 us; speedup vs baseline: 2.7653x; 1.0814x over previous
//
#include <hip/hip_runtime.h>
#include <hip/hip_bf16.h>
#include <math.h>

#define BB 4096
#define DD 256
#define GG 100
#define GAMMA_C 0.8f
#define RHO_C 8.0f
#define ALPHA_C 0.5f
#define EPS_C 1e-14f
#define NSTRIPE 32   // 4096/128 tile stripes

typedef __bf16 bf16x8 __attribute__((ext_vector_type(8)));
typedef float f32x4 __attribute__((ext_vector_type(4)));

__device__ inline void gl2lds16(const void* g, void* l) {
    __builtin_amdgcn_global_load_lds((__attribute__((address_space(1))) void*)(void*)g,
                                     (__attribute__((address_space(3))) void*)l, 16, 0, 0);
}

__device__ inline float blockReduceSum(float v, float* lds) {
    for (int o = 32; o > 0; o >>= 1) v += __shfl_down(v, o);
    int lane = threadIdx.x & 63, wid = threadIdx.x >> 6;
    if (lane == 0) lds[wid] = v;
    __syncthreads();
    if (threadIdx.x == 0) {
        float r = lds[0];
        int nw = blockDim.x >> 6;
        for (int w = 1; w < nw; w++) r += lds[w];
        lds[0] = r;
    }
    __syncthreads();
    float r = lds[0];
    __syncthreads();
    return r;
}

// ---------------- 1) L2 normalize + split into bf16 hi/lo -------------------
__global__ void norm_kernel(const float* __restrict__ zis,
                            const float* __restrict__ zjs,
                            ushort* __restrict__ zhi, ushort* __restrict__ zlo,
                            ushort* __restrict__ whi, ushort* __restrict__ wlo) {
    __shared__ float lds[8];
    int r = blockIdx.x;
    const float* src;
    ushort *dhi, *dlo;
    int row;
    if (r < BB) { src = zis; dhi = zhi; dlo = zlo; row = r; }
    else        { src = zjs; dhi = whi; dlo = wlo; row = r - BB; }
    float v = src[row * DD + threadIdx.x];
    float ss = blockReduceSum(v * v, lds);
    float inv = 1.0f / fmaxf(sqrtf(ss), 1e-12f);
    float nv = v * inv;
    __hip_bfloat16 h = __float2bfloat16(nv);
    float hf = __bfloat162float(h);
    __hip_bfloat16 l = __float2bfloat16(nv - hf);
    dhi[row * DD + threadIdx.x] = *(ushort*)&h;
    dlo[row * DD + threadIdx.x] = *(ushort*)&l;
}

// ---------------- 2) phase 1: row/col max partials + diag (hi*hi only) ------
// bnew derived from hi-only sim is valid: loss/F are invariant to the exact
// max used (all exp terms rescale consistently); error<=4e-3 -> exponent
// slack <=0.4, no overflow risk.
__global__ void __launch_bounds__(256) phase1_max(const ushort* __restrict__ Ahi,
                                                  const ushort* __restrict__ Bhi,
                                                  float* __restrict__ pmaxR,
                                                  float* __restrict__ pmaxC,
                                                  float* __restrict__ diag) {
    __shared__ ushort sAhi[128 * 32];
    __shared__ ushort sBhi[128 * 32];
    __shared__ float redR[128][2];
    __shared__ float redC[128][2];

    int lane = threadIdx.x & 63;
    int wv = threadIdx.x >> 6;
    int wm = wv >> 1, wn = wv & 1;
    int bm = blockIdx.y * 128, bn = blockIdx.x * 128;
    int ml = lane & 15, kq = lane >> 4;
    int koff = kq * 8;

    f32x4 acc[4][4] = {};
    for (int k0 = 0; k0 < DD; k0 += 32) {
        for (int i = 0; i < 2; i++) {
            int cbase = i * 256 + wv * 64;
            int c = cbase + lane;
            int row = c >> 2;
            int col = (c & 3) * 8;
            size_t ga = (size_t)(bm + row) * DD + k0 + col;
            size_t gb = (size_t)(bn + row) * DD + k0 + col;
            int lofs = cbase * 8;
            gl2lds16(&Ahi[ga], &sAhi[lofs]);
            gl2lds16(&Bhi[gb], &sBhi[lofs]);
        }
        __syncthreads();
        bf16x8 ah[4], bh[4];
        for (int t = 0; t < 4; t++) {
            ah[t] = *(const bf16x8*)&sAhi[(wm * 64 + t * 16 + ml) * 32 + koff];
            bh[t] = *(const bf16x8*)&sBhi[(wn * 64 + t * 16 + ml) * 32 + koff];
        }
        for (int t = 0; t < 4; t++)
            for (int u = 0; u < 4; u++)
                acc[t][u] = __builtin_amdgcn_mfma_f32_16x16x32_bf16(ah[t], bh[u], acc[t][u], 0, 0, 0);
        __syncthreads();
    }

    // diag extraction (diagonal blocks only)
    if (blockIdx.x == blockIdx.y && wm == wn) {
        for (int t = 0; t < 4; t++)
            for (int reg = 0; reg < 4; reg++)
                if (ml == kq * 4 + reg)
                    diag[bm + wm * 64 + t * 16 + kq * 4 + reg] = acc[t][t][reg];
    }

    // row max partials (max over this block's 128 cols)
    for (int t = 0; t < 4; t++) {
        float rg[4];
        for (int reg = 0; reg < 4; reg++) {
            float m = fmaxf(fmaxf(acc[t][0][reg], acc[t][1][reg]),
                            fmaxf(acc[t][2][reg], acc[t][3][reg]));
            rg[reg] = m;
        }
        for (int mask = 1; mask <= 8; mask <<= 1)
            for (int reg = 0; reg < 4; reg++)
                rg[reg] = fmaxf(rg[reg], __shfl_xor(rg[reg], mask));
        if (ml == 0)
            for (int reg = 0; reg < 4; reg++)
                redR[wm * 64 + t * 16 + kq * 4 + reg][wn] = rg[reg];
    }
    // col max partials
    float cm[4];
    for (int u = 0; u < 4; u++) {
        float m = -INFINITY;
        for (int t = 0; t < 4; t++)
            for (int reg = 0; reg < 4; reg++)
                m = fmaxf(m, acc[t][u][reg]);
        cm[u] = m;
    }
    for (int mask = 16; mask <= 32; mask <<= 1)
        for (int u = 0; u < 4; u++)
            cm[u] = fmaxf(cm[u], __shfl_xor(cm[u], mask));
    if (kq == 0)
        for (int u = 0; u < 4; u++)
            redC[wn * 64 + u * 16 + ml][wm] = cm[u];
    __syncthreads();
    if (threadIdx.x < 128) {
        pmaxR[(size_t)blockIdx.x * BB + bm + threadIdx.x] =
            fmaxf(redR[threadIdx.x][0], redR[threadIdx.x][1]);
        pmaxC[(size_t)blockIdx.y * BB + bn + threadIdx.x] =
            fmaxf(redC[threadIdx.x][0], redC[threadIdx.x][1]);
    }
}

// ---------------- 3) bnew per row / col -------------------------------------
__global__ void __launch_bounds__(256) bnew_kernel(const float* __restrict__ pmaxR,
        const float* __restrict__ pmaxC, const float* __restrict__ diag,
        const float* __restrict__ bI, const float* __restrict__ bT,
        const float* __restrict__ tausI, const float* __restrict__ tausT,
        const int* __restrict__ ids,
        float* __restrict__ bnewI, float* __restrict__ bnewT) {
    int i = blockIdx.x * 256 + threadIdx.x;
    float rm = -INFINITY, cm = -INFINITY;
    for (int s = 0; s < NSTRIPE; s++) {
        rm = fmaxf(rm, pmaxR[(size_t)s * BB + i]);
        cm = fmaxf(cm, pmaxC[(size_t)s * BB + i]);
    }
    int id = ids[i];
    float d = diag[i];
    bnewI[i] = fmaxf((rm - d) * (1.0f / tausI[id]), bI[id]);
    bnewT[i] = fmaxf((cm - d) * (1.0f / tausT[id]), bT[id]);
}

// ---------------- 4) phase 2: recompute sim (3-MFMA), exp-sum partials ------
__global__ void __launch_bounds__(256) phase2_sum(const ushort* __restrict__ Ahi,
        const ushort* __restrict__ Alo, const ushort* __restrict__ Bhi,
        const ushort* __restrict__ Blo, const float* __restrict__ diag,
        const float* __restrict__ bnewI, const float* __restrict__ bnewT,
        const float* __restrict__ tausI, const float* __restrict__ tausT,
        const int* __restrict__ ids,
        float* __restrict__ pgI, float* __restrict__ pwI,
        float* __restrict__ pgT, float* __restrict__ pwT) {
    __shared__ ushort sAhi[128 * 32];
    __shared__ ushort sAlo[128 * 32];
    __shared__ ushort sBhi[128 * 32];
    __shared__ ushort sBlo[128 * 32];
    __shared__ float rDiag[128], rITau[128], rB[128];
    __shared__ float cDiag[128], cITau[128], cB[128];
    __shared__ float redG[128][2], redW[128][2];
    __shared__ float redCG[128][2], redCW[128][2];

    int lane = threadIdx.x & 63;
    int wv = threadIdx.x >> 6;
    int wm = wv >> 1, wn = wv & 1;
    int bm = blockIdx.y * 128, bn = blockIdx.x * 128;
    int ml = lane & 15, kq = lane >> 4;
    int koff = kq * 8;

    // preload per-row / per-col params (ordered before use by first sync)
    if (threadIdx.x < 128) {
        int r = bm + threadIdx.x;
        rDiag[threadIdx.x] = diag[r];
        rITau[threadIdx.x] = 1.0f / tausI[ids[r]];
        rB[threadIdx.x] = bnewI[r];
    } else {
        int c = bn + threadIdx.x - 128;
        cDiag[threadIdx.x - 128] = diag[c];
        cITau[threadIdx.x - 128] = 1.0f / tausT[ids[c]];
        cB[threadIdx.x - 128] = bnewT[c];
    }

    f32x4 acc[4][4] = {};
    for (int k0 = 0; k0 < DD; k0 += 32) {
        for (int i = 0; i < 2; i++) {
            int cbase = i * 256 + wv * 64;
            int c = cbase + lane;
            int row = c >> 2;
            int col = (c & 3) * 8;
            size_t ga = (size_t)(bm + row) * DD + k0 + col;
            size_t gb = (size_t)(bn + row) * DD + k0 + col;
            int lofs = cbase * 8;
            gl2lds16(&Ahi[ga], &sAhi[lofs]);
            gl2lds16(&Alo[ga], &sAlo[lofs]);
            gl2lds16(&Bhi[gb], &sBhi[lofs]);
            gl2lds16(&Blo[gb], &sBlo[lofs]);
        }
        __syncthreads();
        bf16x8 ah[4], al[4], bh[4], bl[4];
        for (int t = 0; t < 4; t++) {
            int ar = wm * 64 + t * 16 + ml;
            ah[t] = *(const bf16x8*)&sAhi[ar * 32 + koff];
            al[t] = *(const bf16x8*)&sAlo[ar * 32 + koff];
            int br = wn * 64 + t * 16 + ml;
            bh[t] = *(const bf16x8*)&sBhi[br * 32 + koff];
            bl[t] = *(const bf16x8*)&sBlo[br * 32 + koff];
        }
        for (int t = 0; t < 4; t++)
            for (int u = 0; u < 4; u++) {
                acc[t][u] = __builtin_amdgcn_mfma_f32_16x16x32_bf16(ah[t], bh[u], acc[t][u], 0, 0, 0);
                acc[t][u] = __builtin_amdgcn_mfma_f32_16x16x32_bf16(ah[t], bl[u], acc[t][u], 0, 0, 0);
                acc[t][u] = __builtin_amdgcn_mfma_f32_16x16x32_bf16(al[t], bh[u], acc[t][u], 0, 0, 0);
            }
        __syncthreads();
    }

    // epilogue: per-element exp for both sides, reduce to row/col partials
    float cg[4] = {0.f, 0.f, 0.f, 0.f}, cw[4] = {0.f, 0.f, 0.f, 0.f};
    for (int t = 0; t < 4; t++) {
        int rl0 = wm * 64 + t * 16 + kq * 4;
        float rd[4], rit[4], rb[4];
        for (int reg = 0; reg < 4; reg++) {
            rd[reg] = rDiag[rl0 + reg];
            rit[reg] = rITau[rl0 + reg];
            rb[reg] = rB[rl0 + reg];
        }
        float rg[4] = {0.f, 0.f, 0.f, 0.f}, rw[4] = {0.f, 0.f, 0.f, 0.f};
        for (int u = 0; u < 4; u++) {
            int cl = wn * 64 + u * 16 + ml;
            float cd = cDiag[cl], cit = cITau[cl], cb = cB[cl];
            for (int reg = 0; reg < 4; reg++) {
                float v = acc[t][u][reg];
                bool off = (bm + rl0 + reg) != (bn + cl);
                float dvI = v - rd[reg];
                float eI = off ? __expf(dvI * rit[reg] - rb[reg]) : 0.f;
                rg[reg] += eI;
                rw[reg] += eI * dvI;
                float dvT = v - cd;
                float eT = off ? __expf(dvT * cit - cb) : 0.f;
                cg[u] += eT;
                cw[u] += eT * dvT;
            }
        }
        for (int mask = 1; mask <= 8; mask <<= 1)
            for (int reg = 0; reg < 4; reg++) {
                rg[reg] += __shfl_xor(rg[reg], mask);
                rw[reg] += __shfl_xor(rw[reg], mask);
            }
        if (ml == 0)
            for (int reg = 0; reg < 4; reg++) {
                redG[rl0 + reg][wn] = rg[reg];
                redW[rl0 + reg][wn] = rw[reg];
            }
    }
    for (int mask = 16; mask <= 32; mask <<= 1)
        for (int u = 0; u < 4; u++) {
            cg[u] += __shfl_xor(cg[u], mask);
            cw[u] += __shfl_xor(cw[u], mask);
        }
    if (kq == 0)
        for (int u = 0; u < 4; u++) {
            int cl = wn * 64 + u * 16 + ml;
            redCG[cl][wm] = cg[u];
            redCW[cl][wm] = cw[u];
        }
    __syncthreads();
    if (threadIdx.x < 128) {
        pgI[(size_t)blockIdx.x * BB + bm + threadIdx.x] = redG[threadIdx.x][0] + redG[threadIdx.x][1];
        pwI[(size_t)blockIdx.x * BB + bm + threadIdx.x] = redW[threadIdx.x][0] + redW[threadIdx.x][1];
        pgT[(size_t)blockIdx.y * BB + bn + threadIdx.x] = redCG[threadIdx.x][0] + redCG[threadIdx.x][1];
        pwT[(size_t)blockIdx.y * BB + bn + threadIdx.x] = redCW[threadIdx.x][0] + redCW[threadIdx.x][1];
    }
}

// acc layout: [0]=lossI [1]=lossT [2..101]=gradI [102..201]=cntI
//             [202..301]=gradT [302..401]=cntT
// ---------------- 5) finalize rows / cols (block-reduced atomics) -----------
__global__ void __launch_bounds__(256) fin_kernel(const float* __restrict__ pg,
        const float* __restrict__ pw, const float* __restrict__ bnew,
        const float* __restrict__ sS, const float* __restrict__ bS,
        const float* __restrict__ taus, const int* __restrict__ ids,
        const int* __restrict__ ginfo, const float* __restrict__ pP,
        float* __restrict__ acc, int side) {
    __shared__ float lds[8];
    __shared__ float binF[GG], binC[GG];
    if (threadIdx.x < GG) { binF[threadIdx.x] = 0.f; binC[threadIdx.x] = 0.f; }
    __syncthreads();
    int i = blockIdx.x * 256 + threadIdx.x;
    float g = 0.f, wsum = 0.f;
    for (int s = 0; s < NSTRIPE; s++) {
        g += pg[(size_t)s * BB + i];
        wsum += pw[(size_t)s * BB + i];
    }
    int id = ids[i];
    float tau = taus[id];
    float bn = bnew[i];
    float snew = (1.f - GAMMA_C) * sS[id] * expf(bS[id] - bn) + GAMMA_C * g;
    float sc = fmaxf(snew, EPS_C);
    int gid = ginfo[id];
    float gw = (float)GG * pP[gid];
    float loss = gw * wsum / sc;
    float F = tau * (logf(sc) + bn + RHO_C);
    atomicAdd(&binF[gid], F);
    atomicAdd(&binC[gid], 1.0f);
    float lsum = blockReduceSum(loss, lds);
    if (threadIdx.x == 0) atomicAdd(&acc[side], lsum);
    __syncthreads();
    if (threadIdx.x < GG) {
        atomicAdd(&acc[2 + side * 200 + threadIdx.x], binF[threadIdx.x]);
        atomicAdd(&acc[102 + side * 200 + threadIdx.x], binC[threadIdx.x]);
    }
}

// ---------------- 6) finalize: p updates + total loss -----------------------
__global__ void final_kernel(const float* __restrict__ acc,
                             const float* __restrict__ zI, const float* __restrict__ zT,
                             const float* __restrict__ pI, const float* __restrict__ pT,
                             float* __restrict__ out) {
    __shared__ float sumsI[2], sumsT[2];
    int g = threadIdx.x;  // 128 threads
    float npI = 0.f, npT = 0.f;
    if (g < GG) {
        float cntI = fmaxf(acc[102 + g], 1.f);
        float gpI = acc[2 + g] / cntI;
        float zi = (1.f - GAMMA_C) * zI[g] + GAMMA_C * gpI;
        float ghpI = -logf(pI[g] + EPS_C) - 1.f;
        float ti = fminf(fmaxf(zi + ghpI, -5.f), 5.f);
        npI = pI[g] * expf(0.02f * ti);

        float cntT = fmaxf(acc[302 + g], 1.f);
        float gpT = acc[202 + g] / cntT;
        float zt = (1.f - GAMMA_C) * zT[g] + GAMMA_C * gpT;
        float ghpT = -logf(pT[g] + EPS_C) - 1.f;
        float tt = fminf(fmaxf(zt + ghpT, -5.f), 5.f);
        npT = pT[g] * expf(0.02f * tt);
    }
    float vI = npI, vT = npT;
    for (int o = 32; o > 0; o >>= 1) {
        vI += __shfl_down(vI, o);
        vT += __shfl_down(vT, o);
    }
    int wid = threadIdx.x >> 6, lane = threadIdx.x & 63;
    if (lane == 0) { sumsI[wid] = vI; sumsT[wid] = vT; }
    __syncthreads();
    float sumI = sumsI[0] + sumsI[1];
    float sumT = sumsT[0] + sumsT[1];
    if (g < GG) {
        out[1 + g] = npI / sumI;
        out[101 + g] = npT / sumT;
    }
    if (threadIdx.x == 0) {
        out[0] = ALPHA_C * (acc[0] / (float)BB) + (1.f - ALPHA_C) * (acc[1] / (float)BB);
    }
}

extern "C" void kernel_launch(void* const* d_in, const int* in_sizes, int n_in,
                              void* d_out, int out_size, void* d_ws, size_t ws_size,
                              hipStream_t stream) {
    const float* zis   = (const float*)d_in[0];
    const float* zjs   = (const float*)d_in[1];
    const float* s_I   = (const float*)d_in[2];
    const float* s_T   = (const float*)d_in[3];
    const float* b_I   = (const float*)d_in[4];
    const float* b_T   = (const float*)d_in[5];
    const float* z_I   = (const float*)d_in[6];
    const float* z_T   = (const float*)d_in[7];
    const float* p_I   = (const float*)d_in[8];
    const float* p_T   = (const float*)d_in[9];
    const float* tausI = (const float*)d_in[10];
    const float* tausT = (const float*)d_in[11];
    const int*   ids   = (const int*)d_in[12];
    const int*   gInfI = (const int*)d_in[13];
    const int*   gInfT = (const int*)d_in[14];
    float* out = (float*)d_out;

    char* ws = (char*)d_ws;
    ushort* zhi = (ushort*)ws;                         // BB*DD u16 each
    ushort* zlo = zhi + (size_t)BB * DD;
    ushort* whi = zlo + (size_t)BB * DD;
    ushort* wlo = whi + (size_t)BB * DD;
    float* acc   = (float*)(wlo + (size_t)BB * DD);    // 402 (pad 512)
    float* diag  = acc + 512;                          // BB
    float* bnewI = diag + BB;                          // BB
    float* bnewT = bnewI + BB;                         // BB
    float* pmaxR = bnewT + BB;                         // NSTRIPE*BB
    float* pmaxC = pmaxR + (size_t)NSTRIPE * BB;       // NSTRIPE*BB
    float* pgI   = pmaxC + (size_t)NSTRIPE * BB;       // NSTRIPE*BB
    float* pwI   = pgI + (size_t)NSTRIPE * BB;
    float* pgT   = pwI + (size_t)NSTRIPE * BB;
    float* pwT   = pgT + (size_t)NSTRIPE * BB;

    hipMemsetAsync(acc, 0, 402 * sizeof(float), stream);
    norm_kernel<<<2 * BB, 256, 0, stream>>>(zis, zjs, zhi, zlo, whi, wlo);
    phase1_max<<<dim3(NSTRIPE, NSTRIPE), 256, 0, stream>>>(zhi, whi, pmaxR, pmaxC, diag);
    bnew_kernel<<<BB / 256, 256, 0, stream>>>(pmaxR, pmaxC, diag, b_I, b_T,
                                              tausI, tausT, ids, bnewI, bnewT);
    phase2_sum<<<dim3(NSTRIPE, NSTRIPE), 256, 0, stream>>>(zhi, zlo, whi, wlo, diag,
            bnewI, bnewT, tausI, tausT, ids, pgI, pwI, pgT, pwT);
    fin_kernel<<<BB / 256, 256, 0, stream>>>(pgI, pwI, bnewI, s_I, b_I, tausI, ids,
                                             gInfI, p_I, acc, 0);
    fin_kernel<<<BB / 256, 256, 0, stream>>>(pgT, pwT, bnewT, s_T, b_T, tausT, ids,
                                             gInfT, p_T, acc, 1);
    final_kernel<<<1, 128, 0, stream>>>(acc, z_I, z_T, p_I, p_T, out);
}

// Round 5
// 321.368 us; speedup vs baseline: 2.9840x; 1.0791x over previous
//
#include <hip/hip_runtime.h>
#include <hip/hip_bf16.h>
#include <math.h>

#define BB 4096
#define DD 256
#define GG 100
#define GAMMA_C 0.8f
#define RHO_C 8.0f
#define ALPHA_C 0.5f
#define EPS_C 1e-14f
#define NS2 64   // 64 stripes (2 per 128-tile: one per 64-wide wave)

typedef __bf16 bf16x8 __attribute__((ext_vector_type(8)));
typedef float f32x4 __attribute__((ext_vector_type(4)));

__device__ inline void gl2lds16(const void* g, void* l) {
    __builtin_amdgcn_global_load_lds((__attribute__((address_space(1))) void*)(void*)g,
                                     (__attribute__((address_space(3))) void*)l, 16, 0, 0);
}

__device__ inline float blockReduceSum(float v, float* lds) {
    for (int o = 32; o > 0; o >>= 1) v += __shfl_down(v, o);
    int lane = threadIdx.x & 63, wid = threadIdx.x >> 6;
    if (lane == 0) lds[wid] = v;
    __syncthreads();
    if (threadIdx.x == 0) {
        float r = lds[0];
        int nw = blockDim.x >> 6;
        for (int w = 1; w < nw; w++) r += lds[w];
        lds[0] = r;
    }
    __syncthreads();
    float r = lds[0];
    __syncthreads();
    return r;
}

// ---------------- 1) normalize both rows, split bf16 hi/lo, diag, zero acc --
// grid BB blocks x 256 threads; block r handles zis[r] AND zjs[r]
__global__ void norm_kernel(const float* __restrict__ zis,
                            const float* __restrict__ zjs,
                            ushort* __restrict__ zhi, ushort* __restrict__ zlo,
                            ushort* __restrict__ whi, ushort* __restrict__ wlo,
                            float* __restrict__ diag, float* __restrict__ acc) {
    __shared__ float lds[8];
    int r = blockIdx.x;
    if (r == 0) { acc[threadIdx.x] = 0.f; acc[threadIdx.x + 256] = 0.f; }
    float zv = zis[r * DD + threadIdx.x];
    float wv = zjs[r * DD + threadIdx.x];
    float sz = blockReduceSum(zv * zv, lds);
    float sw = blockReduceSum(wv * wv, lds);
    float nz = zv * (1.0f / fmaxf(sqrtf(sz), 1e-12f));
    float nw = wv * (1.0f / fmaxf(sqrtf(sw), 1e-12f));
    float dt = blockReduceSum(nz * nw, lds);
    if (threadIdx.x == 0) diag[r] = dt;   // exact fp32 diagonal of sim
    __hip_bfloat16 hz = __float2bfloat16(nz);
    __hip_bfloat16 lz = __float2bfloat16(nz - __bfloat162float(hz));
    __hip_bfloat16 hw = __float2bfloat16(nw);
    __hip_bfloat16 lw = __float2bfloat16(nw - __bfloat162float(hw));
    zhi[r * DD + threadIdx.x] = *(ushort*)&hz;
    zlo[r * DD + threadIdx.x] = *(ushort*)&lz;
    whi[r * DD + threadIdx.x] = *(ushort*)&hw;
    wlo[r * DD + threadIdx.x] = *(ushort*)&lw;
}

// ---------------- 2) fused tile: 3-MFMA sim + local-max exp partials --------
// Flash-style: each wave computes its own local max (bloc, idt units) per
// 64-row/64-col stripe, exponentiates vs bloc, stores (bloc, g, w) partials.
// fin rescales by exp(bloc - bfin) -> identical to global-max reference.
__global__ void __launch_bounds__(256) fused_tile(const ushort* __restrict__ Ahi,
        const ushort* __restrict__ Alo, const ushort* __restrict__ Bhi,
        const ushort* __restrict__ Blo, const float* __restrict__ diag,
        const float* __restrict__ tausI, const float* __restrict__ tausT,
        const int* __restrict__ ids,
        float* __restrict__ pmR, float* __restrict__ pgR, float* __restrict__ pwR,
        float* __restrict__ pmC, float* __restrict__ pgC, float* __restrict__ pwC) {
    __shared__ ushort sAhi[128 * 32];
    __shared__ ushort sAlo[128 * 32];
    __shared__ ushort sBhi[128 * 32];
    __shared__ ushort sBlo[128 * 32];
    __shared__ float rDiag[128], rITau[128];
    __shared__ float cDiag[128], cITau[128];

    int lane = threadIdx.x & 63;
    int wv = threadIdx.x >> 6;
    int wm = wv >> 1, wn = wv & 1;
    int bm = blockIdx.y * 128, bn = blockIdx.x * 128;
    int ml = lane & 15, kq = lane >> 4;
    int koff = kq * 8;

    if (threadIdx.x < 128) {
        int r = bm + threadIdx.x;
        rDiag[threadIdx.x] = diag[r];
        rITau[threadIdx.x] = 1.0f / tausI[ids[r]];
    } else {
        int c = bn + threadIdx.x - 128;
        cDiag[threadIdx.x - 128] = diag[c];
        cITau[threadIdx.x - 128] = 1.0f / tausT[ids[c]];
    }

    f32x4 acc[4][4] = {};
    for (int k0 = 0; k0 < DD; k0 += 32) {
        for (int i = 0; i < 2; i++) {
            int cbase = i * 256 + wv * 64;
            int c = cbase + lane;
            int row = c >> 2;
            int col = (c & 3) * 8;
            size_t ga = (size_t)(bm + row) * DD + k0 + col;
            size_t gb = (size_t)(bn + row) * DD + k0 + col;
            int lofs = cbase * 8;
            gl2lds16(&Ahi[ga], &sAhi[lofs]);
            gl2lds16(&Alo[ga], &sAlo[lofs]);
            gl2lds16(&Bhi[gb], &sBhi[lofs]);
            gl2lds16(&Blo[gb], &sBlo[lofs]);
        }
        __syncthreads();
        bf16x8 ah[4], al[4], bh[4], bl[4];
        for (int t = 0; t < 4; t++) {
            int ar = wm * 64 + t * 16 + ml;
            ah[t] = *(const bf16x8*)&sAhi[ar * 32 + koff];
            al[t] = *(const bf16x8*)&sAlo[ar * 32 + koff];
            int br = wn * 64 + t * 16 + ml;
            bh[t] = *(const bf16x8*)&sBhi[br * 32 + koff];
            bl[t] = *(const bf16x8*)&sBlo[br * 32 + koff];
        }
        for (int t = 0; t < 4; t++)
            for (int u = 0; u < 4; u++) {
                acc[t][u] = __builtin_amdgcn_mfma_f32_16x16x32_bf16(ah[t], bh[u], acc[t][u], 0, 0, 0);
                acc[t][u] = __builtin_amdgcn_mfma_f32_16x16x32_bf16(ah[t], bl[u], acc[t][u], 0, 0, 0);
                acc[t][u] = __builtin_amdgcn_mfma_f32_16x16x32_bf16(al[t], bh[u], acc[t][u], 0, 0, 0);
            }
        __syncthreads();
    }

    // ---- epilogue ----
    // per-lane row params: rows wm*64 + t*16 + kq*4 + reg
    float rd[4][4], rit[4][4];
    for (int t = 0; t < 4; t++)
        for (int reg = 0; reg < 4; reg++) {
            int rl = wm * 64 + t * 16 + kq * 4 + reg;
            rd[t][reg] = rDiag[rl];
            rit[t][reg] = rITau[rl];
        }
    // row-local max (over this wave's 64 cols), in idt units; max includes
    // the diagonal element (idt_ii = 0) exactly like the reference.
    float blocR[4][4];
    for (int t = 0; t < 4; t++)
        for (int reg = 0; reg < 4; reg++) {
            float m = fmaxf(fmaxf(acc[t][0][reg], acc[t][1][reg]),
                            fmaxf(acc[t][2][reg], acc[t][3][reg]));
            for (int mask = 1; mask <= 8; mask <<= 1)
                m = fmaxf(m, __shfl_xor(m, mask));
            blocR[t][reg] = (m - rd[t][reg]) * rit[t][reg];
        }
    // col-local max (over this wave's 64 rows)
    float cd[4], cit[4], cbloc[4];
    for (int u = 0; u < 4; u++) {
        int cl = wn * 64 + u * 16 + ml;
        cd[u] = cDiag[cl];
        cit[u] = cITau[cl];
        float m = -INFINITY;
        for (int t = 0; t < 4; t++)
            for (int reg = 0; reg < 4; reg++)
                m = fmaxf(m, acc[t][u][reg]);
        for (int mask = 16; mask <= 32; mask <<= 1)
            m = fmaxf(m, __shfl_xor(m, mask));
        cbloc[u] = (m - cd[u]) * cit[u];
    }
    // exp pass vs local maxes
    float rg[4][4] = {}, rw[4][4] = {}, cg[4] = {}, cw[4] = {};
    for (int t = 0; t < 4; t++) {
        int gr0 = bm + wm * 64 + t * 16 + kq * 4;
        for (int u = 0; u < 4; u++) {
            int gc = bn + wn * 64 + u * 16 + ml;
            for (int reg = 0; reg < 4; reg++) {
                float v = acc[t][u][reg];
                bool off = (gr0 + reg) != gc;
                float dvI = v - rd[t][reg];
                float eI = off ? __expf(dvI * rit[t][reg] - blocR[t][reg]) : 0.f;
                rg[t][reg] += eI;
                rw[t][reg] += eI * dvI;
                float dvT = v - cd[u];
                float eT = off ? __expf(dvT * cit[u] - cbloc[u]) : 0.f;
                cg[u] += eT;
                cw[u] += eT * dvT;
            }
        }
    }
    // row reduce across ml lanes + vectorized store (4 rows per kq lane)
    int stripeR = blockIdx.x * 2 + wn;
    for (int t = 0; t < 4; t++) {
        for (int reg = 0; reg < 4; reg++)
            for (int mask = 1; mask <= 8; mask <<= 1) {
                rg[t][reg] += __shfl_xor(rg[t][reg], mask);
                rw[t][reg] += __shfl_xor(rw[t][reg], mask);
            }
        if (ml == 0) {
            size_t o = (size_t)stripeR * BB + bm + wm * 64 + t * 16 + kq * 4;
            *(float4*)&pmR[o] = make_float4(blocR[t][0], blocR[t][1], blocR[t][2], blocR[t][3]);
            *(float4*)&pgR[o] = make_float4(rg[t][0], rg[t][1], rg[t][2], rg[t][3]);
            *(float4*)&pwR[o] = make_float4(rw[t][0], rw[t][1], rw[t][2], rw[t][3]);
        }
    }
    // col reduce across kq lanes + store
    int stripeC = blockIdx.y * 2 + wm;
    for (int u = 0; u < 4; u++) {
        for (int mask = 16; mask <= 32; mask <<= 1) {
            cg[u] += __shfl_xor(cg[u], mask);
            cw[u] += __shfl_xor(cw[u], mask);
        }
        if (kq == 0) {
            size_t o = (size_t)stripeC * BB + bn + wn * 64 + u * 16 + ml;
            pmC[o] = cbloc[u];
            pgC[o] = cg[u];
            pwC[o] = cw[u];
        }
    }
}

// acc layout: [0]=lossI [1]=lossT [2..101]=gradI [102..201]=cntI
//             [202..301]=gradT [302..401]=cntT
// ---------------- 3) finalize both sides (32 blocks: 16 row + 16 col) -------
__global__ void __launch_bounds__(256) fin_kernel(
        const float* __restrict__ pmR, const float* __restrict__ pgR,
        const float* __restrict__ pwR, const float* __restrict__ pmC,
        const float* __restrict__ pgC, const float* __restrict__ pwC,
        const float* __restrict__ sI, const float* __restrict__ bI,
        const float* __restrict__ tausI, const int* __restrict__ gInfI,
        const float* __restrict__ pI,
        const float* __restrict__ sT, const float* __restrict__ bT,
        const float* __restrict__ tausT, const int* __restrict__ gInfT,
        const float* __restrict__ pT,
        const int* __restrict__ ids, float* __restrict__ acc) {
    __shared__ float lds[8];
    __shared__ float binF[GG], binC[GG];
    if (threadIdx.x < GG) { binF[threadIdx.x] = 0.f; binC[threadIdx.x] = 0.f; }
    __syncthreads();
    int side = blockIdx.x >> 4;
    int i = (blockIdx.x & 15) * 256 + threadIdx.x;
    const float* pm = side ? pmC : pmR;
    const float* pg = side ? pgC : pgR;
    const float* pw = side ? pwC : pwR;
    const float* sS = side ? sT : sI;
    const float* bS = side ? bT : bI;
    const float* taus = side ? tausT : tausI;
    const int* ginfo = side ? gInfT : gInfI;
    const float* pP = side ? pT : pI;

    int id = ids[i];
    float oldb = bS[id];
    float m = -INFINITY;
    for (int s = 0; s < NS2; s++) m = fmaxf(m, pm[(size_t)s * BB + i]);
    float bfin = fmaxf(m, oldb);
    float g = 0.f, wsum = 0.f;
    for (int s = 0; s < NS2; s++) {
        float f = __expf(pm[(size_t)s * BB + i] - bfin);
        g += pg[(size_t)s * BB + i] * f;
        wsum += pw[(size_t)s * BB + i] * f;
    }
    float tau = taus[id];
    float snew = (1.f - GAMMA_C) * sS[id] * expf(oldb - bfin) + GAMMA_C * g;
    float sc = fmaxf(snew, EPS_C);
    int gid = ginfo[id];
    float gw = (float)GG * pP[gid];
    float loss = gw * wsum / sc;
    float F = tau * (logf(sc) + bfin + RHO_C);
    atomicAdd(&binF[gid], F);
    atomicAdd(&binC[gid], 1.0f);
    float lsum = blockReduceSum(loss, lds);
    if (threadIdx.x == 0) atomicAdd(&acc[side], lsum);
    __syncthreads();
    if (threadIdx.x < GG) {
        atomicAdd(&acc[2 + side * 200 + threadIdx.x], binF[threadIdx.x]);
        atomicAdd(&acc[102 + side * 200 + threadIdx.x], binC[threadIdx.x]);
    }
}

// ---------------- 4) finalize: p updates + total loss -----------------------
__global__ void final_kernel(const float* __restrict__ acc,
                             const float* __restrict__ zI, const float* __restrict__ zT,
                             const float* __restrict__ pI, const float* __restrict__ pT,
                             float* __restrict__ out) {
    __shared__ float sumsI[2], sumsT[2];
    int g = threadIdx.x;  // 128 threads
    float npI = 0.f, npT = 0.f;
    if (g < GG) {
        float cntI = fmaxf(acc[102 + g], 1.f);
        float gpI = acc[2 + g] / cntI;
        float zi = (1.f - GAMMA_C) * zI[g] + GAMMA_C * gpI;
        float ghpI = -logf(pI[g] + EPS_C) - 1.f;
        float ti = fminf(fmaxf(zi + ghpI, -5.f), 5.f);
        npI = pI[g] * expf(0.02f * ti);

        float cntT = fmaxf(acc[302 + g], 1.f);
        float gpT = acc[202 + g] / cntT;
        float zt = (1.f - GAMMA_C) * zT[g] + GAMMA_C * gpT;
        float ghpT = -logf(pT[g] + EPS_C) - 1.f;
        float tt = fminf(fmaxf(zt + ghpT, -5.f), 5.f);
        npT = pT[g] * expf(0.02f * tt);
    }
    float vI = npI, vT = npT;
    for (int o = 32; o > 0; o >>= 1) {
        vI += __shfl_down(vI, o);
        vT += __shfl_down(vT, o);
    }
    int wid = threadIdx.x >> 6, lane = threadIdx.x & 63;
    if (lane == 0) { sumsI[wid] = vI; sumsT[wid] = vT; }
    __syncthreads();
    float sumI = sumsI[0] + sumsI[1];
    float sumT = sumsT[0] + sumsT[1];
    if (g < GG) {
        out[1 + g] = npI / sumI;
        out[101 + g] = npT / sumT;
    }
    if (threadIdx.x == 0) {
        out[0] = ALPHA_C * (acc[0] / (float)BB) + (1.f - ALPHA_C) * (acc[1] / (float)BB);
    }
}

extern "C" void kernel_launch(void* const* d_in, const int* in_sizes, int n_in,
                              void* d_out, int out_size, void* d_ws, size_t ws_size,
                              hipStream_t stream) {
    const float* zis   = (const float*)d_in[0];
    const float* zjs   = (const float*)d_in[1];
    const float* s_I   = (const float*)d_in[2];
    const float* s_T   = (const float*)d_in[3];
    const float* b_I   = (const float*)d_in[4];
    const float* b_T   = (const float*)d_in[5];
    const float* z_I   = (const float*)d_in[6];
    const float* z_T   = (const float*)d_in[7];
    const float* p_I   = (const float*)d_in[8];
    const float* p_T   = (const float*)d_in[9];
    const float* tausI = (const float*)d_in[10];
    const float* tausT = (const float*)d_in[11];
    const int*   ids   = (const int*)d_in[12];
    const int*   gInfI = (const int*)d_in[13];
    const int*   gInfT = (const int*)d_in[14];
    float* out = (float*)d_out;

    char* ws = (char*)d_ws;
    ushort* zhi = (ushort*)ws;                         // BB*DD u16 each
    ushort* zlo = zhi + (size_t)BB * DD;
    ushort* whi = zlo + (size_t)BB * DD;
    ushort* wlo = whi + (size_t)BB * DD;
    float* acc  = (float*)(wlo + (size_t)BB * DD);     // 512
    float* diag = acc + 512;                           // BB
    float* pmR  = diag + BB;                           // NS2*BB each
    float* pgR  = pmR + (size_t)NS2 * BB;
    float* pwR  = pgR + (size_t)NS2 * BB;
    float* pmC  = pwR + (size_t)NS2 * BB;
    float* pgC  = pmC + (size_t)NS2 * BB;
    float* pwC  = pgC + (size_t)NS2 * BB;

    norm_kernel<<<BB, 256, 0, stream>>>(zis, zjs, zhi, zlo, whi, wlo, diag, acc);
    fused_tile<<<dim3(32, 32), 256, 0, stream>>>(zhi, zlo, whi, wlo, diag,
            tausI, tausT, ids, pmR, pgR, pwR, pmC, pgC, pwC);
    fin_kernel<<<32, 256, 0, stream>>>(pmR, pgR, pwR, pmC, pgC, pwC,
            s_I, b_I, tausI, gInfI, p_I, s_T, b_T, tausT, gInfT, p_T, ids, acc);
    final_kernel<<<1, 128, 0, stream>>>(acc, z_I, z_T, p_I, p_T, out);
}